// Round 10
// baseline (127.725 us; speedup 1.0000x reference)
//
#include <hip/hip_runtime.h>
#include <hip/hip_bf16.h>

#define BB 16
#define CC 512
#define NN 1024
#define GG 8
#define HHH 8
#define DH 64

typedef __bf16 bf16x8 __attribute__((ext_vector_type(8)));
typedef float f32x4 __attribute__((ext_vector_type(4)));
typedef float f32x16 __attribute__((ext_vector_type(16)));
typedef unsigned int u32x4 __attribute__((ext_vector_type(4)));

// scale * log2(e), folded into Q at projection time so S' = q'.k is the exp2 argument
#define QSCALE 0.18033688011116027f

__device__ __forceinline__ unsigned short bfb(float f) {
    __hip_bfloat16 h = __float2bfloat16(f);
    return __builtin_bit_cast(unsigned short, h);
}

__device__ __forceinline__ bf16x8 ldb8(const void* p) {
    return *reinterpret_cast<const bf16x8*>(p);
}

__device__ __forceinline__ unsigned int cvtpk(float lo, float hi) {
    unsigned int r;
    asm("v_cvt_pk_bf16_f32 %0, %1, %2" : "=v"(r) : "v"(lo), "v"(hi));
    return r;
}

typedef const __attribute__((address_space(1))) unsigned int* gas_ptr;
typedef __attribute__((address_space(3))) unsigned int* las_ptr;
__device__ __forceinline__ void gload_lds16(const void* g, void* l) {
    __builtin_amdgcn_global_load_lds((gas_ptr)g, (las_ptr)l, 16, 0, 0);
}

// ---------------- kernel A: GN partial stats (blocks 0..511) + weight conversion (512..767) ----------------
__global__ __launch_bounds__(256) void statsconv_kernel(
    const float* __restrict__ x,
    const float4* __restrict__ wq, const float4* __restrict__ wk,
    const float4* __restrict__ wv, const float4* __restrict__ wo,
    ushort4* __restrict__ oq, ushort4* __restrict__ ok2,
    ushort4* __restrict__ ov, ushort4* __restrict__ oo,
    float* __restrict__ part) {
    int blk = blockIdx.x;
    int t = threadIdx.x;
    if (blk < 512) {
        int bg = blk >> 2, q = blk & 3;
        const float* xg = x + (size_t)bg * 65536 + q * 256;  // 64 rows x 256 cols quarter
        float s = 0.f, s2 = 0.f;
        #pragma unroll
        for (int i = 0; i < 16; ++i) {
            int c = i * 256 + t;           // 4096 float4 chunks
            int row = c >> 6, col = c & 63;
            float4 v = *reinterpret_cast<const float4*>(xg + (size_t)row * 1024 + col * 4);
            s += v.x + v.y + v.z + v.w;
            s2 += v.x * v.x + v.y * v.y + v.z * v.z + v.w * v.w;
        }
        #pragma unroll
        for (int m = 1; m < 64; m <<= 1) {
            s += __shfl_xor(s, m);
            s2 += __shfl_xor(s2, m);
        }
        __shared__ float red[2][4];
        int wid = t >> 6;
        if ((t & 63) == 0) { red[0][wid] = s; red[1][wid] = s2; }
        __syncthreads();
        if (t == 0) {
            part[blk * 2 + 0] = red[0][0] + red[0][1] + red[0][2] + red[0][3];
            part[blk * 2 + 1] = red[1][0] + red[1][1] + red[1][2] + red[1][3];
        }
    } else {
        int i = (blk - 512) * 256 + t;     // over C*C/4 = 65536
        float4 a;
        ushort4 r;
        a = wq[i]; r.x = bfb(a.x); r.y = bfb(a.y); r.z = bfb(a.z); r.w = bfb(a.w); oq[i] = r;
        a = wk[i]; r.x = bfb(a.x); r.y = bfb(a.y); r.z = bfb(a.z); r.w = bfb(a.w); ok2[i] = r;
        a = wv[i]; r.x = bfb(a.x); r.y = bfb(a.y); r.z = bfb(a.z); r.w = bfb(a.w); ov[i] = r;
        a = wo[i]; r.x = bfb(a.x); r.y = bfb(a.y); r.z = bfb(a.z); r.w = bfb(a.w); oo[i] = r;
    }
}

// ---------------- kernel B: GN apply + transpose -> xnT [B][N][C] bf16 (512 blocks) ----------------
__global__ __launch_bounds__(256) void gn_apply_kernel(
    const float* __restrict__ x, const float* __restrict__ gamma,
    const float* __restrict__ beta, const float* __restrict__ part,
    unsigned short* __restrict__ xnT) {
    int blk = blockIdx.x;
    int bg = blk >> 2, q = blk & 3;
    int b = bg >> 3, g = bg & 7;
    const float* xg = x + (size_t)bg * 65536;
    int t = threadIdx.x;

    // finalize stats from the 4 quarter-partials (fixed order -> deterministic)
    float s = 0.f, s2 = 0.f;
    #pragma unroll
    for (int j = 0; j < 4; ++j) {
        s += part[(bg * 4 + j) * 2 + 0];
        s2 += part[(bg * 4 + j) * 2 + 1];
    }
    float mean = s * (1.f / 65536.f);
    float var = s2 * (1.f / 65536.f) - mean * mean;
    float rstd = rsqrtf(var + 1e-5f);

    __shared__ unsigned short tile[64][68];
    #pragma unroll
    for (int i = 0; i < 4; ++i) {
        int nt = q * 4 + i;
        __syncthreads();
        #pragma unroll
        for (int p = 0; p < 4; ++p) {
            int cc = p * 16 + (t >> 4);
            int nn = (t & 15) * 4;
            float4 v = *reinterpret_cast<const float4*>(&xg[(size_t)cc * NN + nt * 64 + nn]);
            float ga = gamma[g * 64 + cc], be = beta[g * 64 + cc];
            float aa = rstd * ga;
            float c0 = be - mean * aa;
            ushort4 pk;
            pk.x = bfb(v.x * aa + c0);
            pk.y = bfb(v.y * aa + c0);
            pk.z = bfb(v.z * aa + c0);
            pk.w = bfb(v.w * aa + c0);
            *reinterpret_cast<ushort4*>(&tile[cc][nn]) = pk;
        }
        __syncthreads();
        #pragma unroll
        for (int p = 0; p < 16; ++p) {
            int nn = p * 4 + (t >> 6);
            int cc = t & 63;
            xnT[((size_t)b * NN + nt * 64 + nn) * CC + g * 64 + cc] = tile[cc][nn];
        }
    }
}

// ---------------- kernel 2: fused QKV projections, BK=32 LDS-staged GEMM ----------------
// BK=32 -> 32KB LDS -> ~5 blocks/CU (was 2): more cross-block overlap at barrier drain.
// 64B LDS rows; conflict-free slot swizzle: slot ^= (row>>1)&3 (evens cover banks 0-15,
// odds 16-31, distinct slots within each 8-lane phase). Pre-swizzled source + same XOR on read.
__global__ __launch_bounds__(256, 2) void qkv3_kernel(
    const unsigned short* __restrict__ wqb, const unsigned short* __restrict__ wkb,
    const unsigned short* __restrict__ wvb,
    const float* __restrict__ bq, const float* __restrict__ bk, const float* __restrict__ bv,
    const unsigned short* __restrict__ xnT,
    unsigned short* __restrict__ qt, unsigned short* __restrict__ kt,
    unsigned short* __restrict__ vv) {
    int wg = blockIdx.x;
    int xcd = wg & 7, local = wg >> 3;       // local 0..191
    int mloc = local / 12;                    // 0..15
    int rem = local - mloc * 12;
    int n_tile = rem / 3;                     // 0..3
    int p = rem - n_tile * 3;                 // 0..2
    int m_tile = xcd * 16 + mloc;             // 0..127

    const unsigned short* w = (p == 0) ? wqb : (p == 1) ? wkb : wvb;
    const float* bias = (p == 0) ? bq : (p == 1) ? bk : bv;
    int row0 = m_tile * 128;
    int o0t = n_tile * 128;

    __shared__ __align__(16) char As[2][8192];
    __shared__ __align__(16) char Bs[2][8192];

    int t = threadIdx.x;
    int lane = t & 63, wid = t >> 6;

    const char* Ag = (const char*)xnT + (size_t)row0 * 1024;
    const char* Bg = (const char*)w + (size_t)o0t * 1024;

    // staging geometry: inst (wid,j) -> LDS base (wid*2+j)*1024 (linear, wave-uniform);
    // lane covers chunk c; source col pre-swizzled so linear write + XOR read = swizzle.
    int c0 = wid * 128 + lane;                // chunk for j=0 (j=1 adds 64)
    #define SRCOFF(cj) ((size_t)((cj) >> 2) * 1024 + ((((cj) & 3) ^ (((cj) >> 3) & 3)) << 4))
    // row = c>>2, slot = c&3, sw = (row>>1)&3 = (c>>3)&3

    #pragma unroll
    for (int j = 0; j < 2; ++j) {             // stage k0=0 into buf 0
        int cj = c0 + j * 64;
        gload_lds16(Ag + SRCOFF(cj), &As[0][(wid * 2 + j) * 1024]);
        gload_lds16(Bg + SRCOFF(cj), &Bs[0][(wid * 2 + j) * 1024]);
    }
    __syncthreads();

    int wr = wid & 1, wc = wid >> 1;
    int lr = lane & 15, lg = lane >> 4;
    f32x4 acc[4][4] = {};

    for (int ks = 0; ks < 16; ++ks) {
        int cb_ = ks & 1;
        if (ks < 15) {
            int k0b = (ks + 1) * 64;          // byte offset of next K-slice
            #pragma unroll
            for (int j = 0; j < 2; ++j) {
                int cj = c0 + j * 64;
                gload_lds16(Ag + SRCOFF(cj) + k0b, &As[cb_ ^ 1][(wid * 2 + j) * 1024]);
                gload_lds16(Bg + SRCOFF(cj) + k0b, &Bs[cb_ ^ 1][(wid * 2 + j) * 1024]);
            }
        }
        const char* al = As[cb_];
        const char* bl = Bs[cb_];
        bf16x8 wf[4], xf[4];
        #pragma unroll
        for (int r = 0; r < 4; ++r) {
            int row = wc * 64 + r * 16 + lr;
            wf[r] = ldb8(bl + row * 64 + (((lg ^ ((row >> 1) & 3))) << 4));
        }
        #pragma unroll
        for (int c = 0; c < 4; ++c) {
            int row = wr * 64 + c * 16 + lr;
            xf[c] = ldb8(al + row * 64 + (((lg ^ ((row >> 1) & 3))) << 4));
        }
        __builtin_amdgcn_s_setprio(1);
        #pragma unroll
        for (int r = 0; r < 4; ++r)
            #pragma unroll
            for (int c = 0; c < 4; ++c)
                acc[r][c] = __builtin_amdgcn_mfma_f32_16x16x32_bf16(wf[r], xf[c], acc[r][c], 0, 0, 0);
        __builtin_amdgcn_s_setprio(0);
        __syncthreads();
    }
    #undef SRCOFF

    // epilogue
    #pragma unroll
    for (int r = 0; r < 4; ++r) {
        int o0 = o0t + wc * 64 + r * 16 + lg * 4;
        #pragma unroll
        for (int c = 0; c < 4; ++c) {
            int grow = row0 + wr * 64 + c * 16 + lr;
            int b = grow >> 10, n = grow & 1023;
            float v0 = acc[r][c][0] + bias[o0 + 0];
            float v1 = acc[r][c][1] + bias[o0 + 1];
            float v2 = acc[r][c][2] + bias[o0 + 2];
            float v3 = acc[r][c][3] + bias[o0 + 3];
            if (p < 2) {
                if (p == 0) { v0 *= QSCALE; v1 *= QSCALE; v2 *= QSCALE; v3 *= QSCALE; }
                unsigned short* outp = (p == 0) ? qt : kt;
                int h = o0 >> 6, d = o0 & 63;
                ushort4 pk;
                pk.x = bfb(v0); pk.y = bfb(v1); pk.z = bfb(v2); pk.w = bfb(v3);
                *reinterpret_cast<ushort4*>(outp + ((size_t)(b * HHH + h) * NN + n) * DH + d) = pk;
            } else {
                vv[((size_t)b * CC + o0 + 0) * NN + n] = bfb(v0);
                vv[((size_t)b * CC + o0 + 1) * NN + n] = bfb(v1);
                vv[((size_t)b * CC + o0 + 2) * NN + n] = bfb(v2);
                vv[((size_t)b * CC + o0 + 3) * NN + n] = bfb(v3);
            }
        }
    }
}

// ---------------- kernel 3: flash attention, max-free softmax (attn4, best: 47.5us) ----------------
__global__ __launch_bounds__(256, 2) void attn4_kernel(
    const unsigned short* __restrict__ qt, const unsigned short* __restrict__ kt,
    const unsigned short* __restrict__ vv, unsigned short* __restrict__ aoT) {
    int wg = blockIdx.x;
    int bh = ((wg >> 6) << 3) + (wg & 7);  // all 8 qtiles of a head share an XCD
    int qt8 = (wg >> 3) & 7;
    int b = bh >> 3, h = bh & 7;
    int lane = threadIdx.x & 63, wid = threadIdx.x >> 6;
    int nl = lane & 31, hi = lane >> 5;
    int n = qt8 * 128 + wid * 32 + nl;

    const unsigned short* Qb = qt + (size_t)bh * NN * DH;
    const unsigned short* Kb = kt + (size_t)bh * NN * DH;
    const unsigned short* Vb = vv + ((size_t)b * CC + h * DH) * NN;

    __shared__ __align__(16) char smem[2][16384];  // [buf][ K 8KB | V 8KB ]

    const unsigned short* Qp = Qb + (size_t)n * DH + hi * 8;
    bf16x8 qf[4];
    qf[0] = ldb8(Qp);
    qf[1] = ldb8(Qp + 16);
    qf[2] = ldb8(Qp + 32);
    qf[3] = ldb8(Qp + 48);

    int Rl = lane >> 3;                    // 0..7
    int cs16 = 16 * ((lane & 7) ^ Rl);     // pre-swizzled col bytes
    const char* Kc = (const char*)Kb;      // row stride 128B
    const char* Vc = (const char*)Vb;      // row stride 2048B

    #pragma unroll
    for (int j = 0; j < 2; ++j) {
        int ii = 2 * wid + j;
        int R = ii * 8 + Rl;
        gload_lds16(Kc + (size_t)R * 128 + cs16, &smem[0][ii * 1024]);
        gload_lds16(Vc + (size_t)R * 2048 + cs16, &smem[0][8192 + ii * 1024]);
    }
    __syncthreads();

    f32x16 o0 = {}, o1 = {};
    float l_i = 0.f;
    int cur = 0;

    for (int mt = 0; mt < 16; ++mt) {
        if (mt < 15) {
            int m0n = (mt + 1) * 64;
            #pragma unroll
            for (int j = 0; j < 2; ++j) {
                int ii = 2 * wid + j;
                int R = ii * 8 + Rl;
                gload_lds16(Kc + (size_t)(m0n + R) * 128 + cs16, &smem[cur ^ 1][ii * 1024]);
                gload_lds16(Vc + (size_t)R * 2048 + (size_t)m0n * 2 + cs16,
                            &smem[cur ^ 1][8192 + ii * 1024]);
            }
        }

        const char* kl = &smem[cur][0];
        const char* vl = &smem[cur][8192];
        int swz = (nl & 7) << 4;
        int rowA = nl * 128, rowB = (nl + 32) * 128;

        bf16x8 ka[4], kbf[4];
        #pragma unroll
        for (int ks = 0; ks < 4; ++ks) {
            int cb = (hi * 16 + ks * 32) ^ swz;
            ka[ks]  = ldb8(kl + rowA + cb);
            kbf[ks] = ldb8(kl + rowB + cb);
        }

        f32x16 s0 = {}, s1 = {};
        __builtin_amdgcn_s_setprio(1);
        #pragma unroll
        for (int ks = 0; ks < 4; ++ks) {
            s0 = __builtin_amdgcn_mfma_f32_32x32x16_bf16(ka[ks], qf[ks], s0, 0, 0, 0);
            s1 = __builtin_amdgcn_mfma_f32_32x32x16_bf16(kbf[ks], qf[ks], s1, 0, 0, 0);
        }
        __builtin_amdgcn_s_setprio(0);

        bf16x8 va[4], vbf[4];
        #pragma unroll
        for (int ks = 0; ks < 4; ++ks) {
            int cb = (hi * 16 + ks * 32) ^ swz;
            va[ks]  = ldb8(vl + rowA + cb);
            vbf[ks] = ldb8(vl + rowB + cb);
        }

        // ---- max-free softmax: P = 2^S', accumulate l ----
        #pragma unroll
        for (int e = 0; e < 16; ++e) s0[e] = __builtin_amdgcn_exp2f(s0[e]);
        #pragma unroll
        for (int e = 0; e < 16; ++e) s1[e] = __builtin_amdgcn_exp2f(s1[e]);
        float ts[16];
        #pragma unroll
        for (int e = 0; e < 16; ++e) ts[e] = s0[e] + s1[e];
        #pragma unroll
        for (int st = 8; st; st >>= 1)
            #pragma unroll
            for (int e = 0; e < st; ++e) ts[e] += ts[e + st];
        l_i += ts[0];

        // ---- pack P -> bf16 B-fragments (cvt_pk + permlane32_swap) ----
        unsigned pA = cvtpk(s0[0], s0[1]), pB = cvtpk(s0[4], s0[5]);
        asm("v_permlane32_swap_b32 %0, %1" : "+v"(pA), "+v"(pB));
        unsigned pC = cvtpk(s0[2], s0[3]), pD = cvtpk(s0[6], s0[7]);
        asm("v_permlane32_swap_b32 %0, %1" : "+v"(pC), "+v"(pD));
        unsigned pE = cvtpk(s0[8], s0[9]), pF = cvtpk(s0[12], s0[13]);
        asm("v_permlane32_swap_b32 %0, %1" : "+v"(pE), "+v"(pF));
        unsigned pG = cvtpk(s0[10], s0[11]), pH = cvtpk(s0[14], s0[15]);
        asm("v_permlane32_swap_b32 %0, %1" : "+v"(pG), "+v"(pH));
        u32x4 w00 = {pA, pC, pB, pD};
        u32x4 w01 = {pE, pG, pF, pH};
        unsigned qA = cvtpk(s1[0], s1[1]), qB = cvtpk(s1[4], s1[5]);
        asm("v_permlane32_swap_b32 %0, %1" : "+v"(qA), "+v"(qB));
        unsigned qC = cvtpk(s1[2], s1[3]), qD = cvtpk(s1[6], s1[7]);
        asm("v_permlane32_swap_b32 %0, %1" : "+v"(qC), "+v"(qD));
        unsigned qE = cvtpk(s1[8], s1[9]), qF = cvtpk(s1[12], s1[13]);
        asm("v_permlane32_swap_b32 %0, %1" : "+v"(qE), "+v"(qF));
        unsigned qG = cvtpk(s1[10], s1[11]), qH = cvtpk(s1[14], s1[15]);
        asm("v_permlane32_swap_b32 %0, %1" : "+v"(qG), "+v"(qH));
        u32x4 w10 = {qA, qC, qB, qD};
        u32x4 w11 = {qE, qG, qF, qH};

        bf16x8 pa00 = __builtin_bit_cast(bf16x8, w00);
        bf16x8 pa01 = __builtin_bit_cast(bf16x8, w01);
        bf16x8 pa10 = __builtin_bit_cast(bf16x8, w10);
        bf16x8 pa11 = __builtin_bit_cast(bf16x8, w11);

        // ---- PV: O^T[d][n] += V^T[d][m] P^T[m][n] ----
        __builtin_amdgcn_s_setprio(1);
        o0 = __builtin_amdgcn_mfma_f32_32x32x16_bf16(va[0], pa00, o0, 0, 0, 0);
        o0 = __builtin_amdgcn_mfma_f32_32x32x16_bf16(va[1], pa01, o0, 0, 0, 0);
        o0 = __builtin_amdgcn_mfma_f32_32x32x16_bf16(va[2], pa10, o0, 0, 0, 0);
        o0 = __builtin_amdgcn_mfma_f32_32x32x16_bf16(va[3], pa11, o0, 0, 0, 0);
        o1 = __builtin_amdgcn_mfma_f32_32x32x16_bf16(vbf[0], pa00, o1, 0, 0, 0);
        o1 = __builtin_amdgcn_mfma_f32_32x32x16_bf16(vbf[1], pa01, o1, 0, 0, 0);
        o1 = __builtin_amdgcn_mfma_f32_32x32x16_bf16(vbf[2], pa10, o1, 0, 0, 0);
        o1 = __builtin_amdgcn_mfma_f32_32x32x16_bf16(vbf[3], pa11, o1, 0, 0, 0);
        __builtin_amdgcn_s_setprio(0);

        __syncthreads();
        cur ^= 1;
    }

    // merge the hi-half partial denominators once, normalize, write aoT
    float l = l_i + __shfl_xor(l_i, 32);
    float inv = 1.f / l;
    unsigned short* op = aoT + ((size_t)b * NN + n) * CC + h * DH;
    #pragma unroll
    for (int q = 0; q < 4; ++q) {
        ushort4 pk;
        pk.x = bfb(o0[4 * q + 0] * inv);
        pk.y = bfb(o0[4 * q + 1] * inv);
        pk.z = bfb(o0[4 * q + 2] * inv);
        pk.w = bfb(o0[4 * q + 3] * inv);
        *reinterpret_cast<ushort4*>(op + q * 8 + hi * 4) = pk;
        ushort4 pk2;
        pk2.x = bfb(o1[4 * q + 0] * inv);
        pk2.y = bfb(o1[4 * q + 1] * inv);
        pk2.z = bfb(o1[4 * q + 2] * inv);
        pk2.w = bfb(o1[4 * q + 3] * inv);
        *reinterpret_cast<ushort4*>(op + 32 + q * 8 + hi * 4) = pk2;
    }
}

// ---------------- kernel 4: output projection, BK=32 LDS-staged GEMM + bias + residual ----------------
__global__ __launch_bounds__(256, 2) void oproj3_kernel(
    const unsigned short* __restrict__ wob, const float* __restrict__ bo,
    const unsigned short* __restrict__ aoT, const float* __restrict__ x,
    float* __restrict__ out) {
    int wg = blockIdx.x;
    int xcd = wg & 7, local = wg >> 3;        // local 0..63
    int mloc = local >> 2;                     // 0..15
    int n_tile = local & 3;                    // 0..3
    int m_tile = xcd * 16 + mloc;              // 0..127
    int row0 = m_tile * 128;
    int o0t = n_tile * 128;

    __shared__ __align__(16) char As[2][8192];
    __shared__ __align__(16) char Bs[2][8192];

    int t = threadIdx.x;
    int lane = t & 63, wid = t >> 6;

    const char* Ag = (const char*)aoT + (size_t)row0 * 1024;
    const char* Bg = (const char*)wob + (size_t)o0t * 1024;

    int c0 = wid * 128 + lane;
    #define SRCOFF(cj) ((size_t)((cj) >> 2) * 1024 + ((((cj) & 3) ^ (((cj) >> 3) & 3)) << 4))

    #pragma unroll
    for (int j = 0; j < 2; ++j) {
        int cj = c0 + j * 64;
        gload_lds16(Ag + SRCOFF(cj), &As[0][(wid * 2 + j) * 1024]);
        gload_lds16(Bg + SRCOFF(cj), &Bs[0][(wid * 2 + j) * 1024]);
    }
    __syncthreads();

    int wr = wid & 1, wc = wid >> 1;
    int lr = lane & 15, lg = lane >> 4;
    f32x4 acc[4][4] = {};

    for (int ks = 0; ks < 16; ++ks) {
        int cb_ = ks & 1;
        if (ks < 15) {
            int k0b = (ks + 1) * 64;
            #pragma unroll
            for (int j = 0; j < 2; ++j) {
                int cj = c0 + j * 64;
                gload_lds16(Ag + SRCOFF(cj) + k0b, &As[cb_ ^ 1][(wid * 2 + j) * 1024]);
                gload_lds16(Bg + SRCOFF(cj) + k0b, &Bs[cb_ ^ 1][(wid * 2 + j) * 1024]);
            }
        }
        const char* al = As[cb_];
        const char* bl = Bs[cb_];
        bf16x8 wf[4], xf[4];
        #pragma unroll
        for (int r = 0; r < 4; ++r) {
            int row = wc * 64 + r * 16 + lr;
            wf[r] = ldb8(bl + row * 64 + (((lg ^ ((row >> 1) & 3))) << 4));
        }
        #pragma unroll
        for (int c = 0; c < 4; ++c) {
            int row = wr * 64 + c * 16 + lr;
            xf[c] = ldb8(al + row * 64 + (((lg ^ ((row >> 1) & 3))) << 4));
        }
        __builtin_amdgcn_s_setprio(1);
        #pragma unroll
        for (int r = 0; r < 4; ++r)
            #pragma unroll
            for (int c = 0; c < 4; ++c)
                acc[r][c] = __builtin_amdgcn_mfma_f32_16x16x32_bf16(wf[r], xf[c], acc[r][c], 0, 0, 0);
        __builtin_amdgcn_s_setprio(0);
        __syncthreads();
    }
    #undef SRCOFF

    #pragma unroll
    for (int r = 0; r < 4; ++r) {
        int o0 = o0t + wc * 64 + r * 16 + lg * 4;
        #pragma unroll
        for (int c = 0; c < 4; ++c) {
            int grow = row0 + wr * 64 + c * 16 + lr;
            int b = grow >> 10, n = grow & 1023;
            #pragma unroll
            for (int j = 0; j < 4; ++j) {
                size_t idx = ((size_t)b * CC + o0 + j) * NN + n;
                out[idx] = acc[r][c][j] + bo[o0 + j] + x[idx];
            }
        }
    }
}

extern "C" void kernel_launch(void* const* d_in, const int* in_sizes, int n_in,
                              void* d_out, int out_size, void* d_ws, size_t ws_size,
                              hipStream_t stream) {
    const float* x     = (const float*)d_in[0];
    const float* wq    = (const float*)d_in[1];
    const float* bq    = (const float*)d_in[2];
    const float* wk    = (const float*)d_in[3];
    const float* bk    = (const float*)d_in[4];
    const float* wv    = (const float*)d_in[5];
    const float* bv    = (const float*)d_in[6];
    const float* wo    = (const float*)d_in[7];
    const float* bo    = (const float*)d_in[8];
    const float* gamma = (const float*)d_in[9];
    const float* beta  = (const float*)d_in[10];

    char* ws = (char*)d_ws;
    const size_t WSZ = (size_t)CC * CC * 2;           // 512 KB per weight
    const size_t TEN = (size_t)BB * NN * CC * 2;      // 16.78 MB per tensor
    unsigned short* wqb = (unsigned short*)(ws);
    unsigned short* wkb = (unsigned short*)(ws + WSZ);
    unsigned short* wvb = (unsigned short*)(ws + 2 * WSZ);
    unsigned short* wob = (unsigned short*)(ws + 3 * WSZ);
    unsigned short* xnT = (unsigned short*)(ws + 4 * WSZ);
    unsigned short* qt  = (unsigned short*)(ws + 4 * WSZ + TEN);
    unsigned short* kt  = (unsigned short*)(ws + 4 * WSZ + 2 * TEN);
    unsigned short* vv  = (unsigned short*)(ws + 4 * WSZ + 3 * TEN);
    unsigned short* aoT = (unsigned short*)(ws + 4 * WSZ + 4 * TEN);
    float* part         = (float*)(ws + 4 * WSZ + 5 * TEN);   // 512*2 floats

    statsconv_kernel<<<dim3(768), dim3(256), 0, stream>>>(
        x, (const float4*)wq, (const float4*)wk, (const float4*)wv, (const float4*)wo,
        (ushort4*)wqb, (ushort4*)wkb, (ushort4*)wvb, (ushort4*)wob, part);
    gn_apply_kernel<<<dim3(512), dim3(256), 0, stream>>>(x, gamma, beta, part, xnT);
    qkv3_kernel<<<dim3(1536), dim3(256), 0, stream>>>(
        wqb, wkb, wvb, bq, bk, bv, xnT, qt, kt, vv);
    attn4_kernel<<<dim3(1024), dim3(256), 0, stream>>>(qt, kt, vv, aoT);
    oproj3_kernel<<<dim3(512), dim3(256), 0, stream>>>(wob, bo, aoT, x, (float*)d_out);
}

// Round 11
// 123.320 us; speedup vs baseline: 1.0357x; 1.0357x over previous
//
#include <hip/hip_runtime.h>
#include <hip/hip_bf16.h>

#define BB 16
#define CC 512
#define NN 1024
#define GG 8
#define HHH 8
#define DH 64

typedef __bf16 bf16x8 __attribute__((ext_vector_type(8)));
typedef float f32x4 __attribute__((ext_vector_type(4)));
typedef float f32x16 __attribute__((ext_vector_type(16)));
typedef unsigned int u32x4 __attribute__((ext_vector_type(4)));

// scale * log2(e), folded into Q at projection time so S' = q'.k is the exp2 argument
#define QSCALE 0.18033688011116027f

__device__ __forceinline__ unsigned short bfb(float f) {
    __hip_bfloat16 h = __float2bfloat16(f);
    return __builtin_bit_cast(unsigned short, h);
}

__device__ __forceinline__ bf16x8 ldb8(const void* p) {
    return *reinterpret_cast<const bf16x8*>(p);
}

__device__ __forceinline__ unsigned int cvtpk(float lo, float hi) {
    unsigned int r;
    asm("v_cvt_pk_bf16_f32 %0, %1, %2" : "=v"(r) : "v"(lo), "v"(hi));
    return r;
}

typedef const __attribute__((address_space(1))) unsigned int* gas_ptr;
typedef __attribute__((address_space(3))) unsigned int* las_ptr;
__device__ __forceinline__ void gload_lds16(const void* g, void* l) {
    __builtin_amdgcn_global_load_lds((gas_ptr)g, (las_ptr)l, 16, 0, 0);
}

// ---------------- kernel A: GN partial stats (blocks 0..511) + weight conversion (512..767) ----------------
__global__ __launch_bounds__(256) void statsconv_kernel(
    const float* __restrict__ x,
    const float4* __restrict__ wq, const float4* __restrict__ wk,
    const float4* __restrict__ wv, const float4* __restrict__ wo,
    ushort4* __restrict__ oq, ushort4* __restrict__ ok2,
    ushort4* __restrict__ ov, ushort4* __restrict__ oo,
    float* __restrict__ part) {
    int blk = blockIdx.x;
    int t = threadIdx.x;
    if (blk < 512) {
        int bg = blk >> 2, q = blk & 3;
        const float* xg = x + (size_t)bg * 65536 + q * 256;  // 64 rows x 256 cols quarter
        float s = 0.f, s2 = 0.f;
        #pragma unroll
        for (int i = 0; i < 16; ++i) {
            int c = i * 256 + t;           // 4096 float4 chunks
            int row = c >> 6, col = c & 63;
            float4 v = *reinterpret_cast<const float4*>(xg + (size_t)row * 1024 + col * 4);
            s += v.x + v.y + v.z + v.w;
            s2 += v.x * v.x + v.y * v.y + v.z * v.z + v.w * v.w;
        }
        #pragma unroll
        for (int m = 1; m < 64; m <<= 1) {
            s += __shfl_xor(s, m);
            s2 += __shfl_xor(s2, m);
        }
        __shared__ float red[2][4];
        int wid = t >> 6;
        if ((t & 63) == 0) { red[0][wid] = s; red[1][wid] = s2; }
        __syncthreads();
        if (t == 0) {
            part[blk * 2 + 0] = red[0][0] + red[0][1] + red[0][2] + red[0][3];
            part[blk * 2 + 1] = red[1][0] + red[1][1] + red[1][2] + red[1][3];
        }
    } else {
        int i = (blk - 512) * 256 + t;     // over C*C/4 = 65536
        float4 a;
        ushort4 r;
        a = wq[i]; r.x = bfb(a.x); r.y = bfb(a.y); r.z = bfb(a.z); r.w = bfb(a.w); oq[i] = r;
        a = wk[i]; r.x = bfb(a.x); r.y = bfb(a.y); r.z = bfb(a.z); r.w = bfb(a.w); ok2[i] = r;
        a = wv[i]; r.x = bfb(a.x); r.y = bfb(a.y); r.z = bfb(a.z); r.w = bfb(a.w); ov[i] = r;
        a = wo[i]; r.x = bfb(a.x); r.y = bfb(a.y); r.z = bfb(a.z); r.w = bfb(a.w); oo[i] = r;
    }
}

// ---------------- kernel B: GN apply + transpose -> xnT [B][N][C] bf16 (512 blocks) ----------------
__global__ __launch_bounds__(256) void gn_apply_kernel(
    const float* __restrict__ x, const float* __restrict__ gamma,
    const float* __restrict__ beta, const float* __restrict__ part,
    unsigned short* __restrict__ xnT) {
    int blk = blockIdx.x;
    int bg = blk >> 2, q = blk & 3;
    int b = bg >> 3, g = bg & 7;
    const float* xg = x + (size_t)bg * 65536;
    int t = threadIdx.x;

    // finalize stats from the 4 quarter-partials (fixed order -> deterministic)
    float s = 0.f, s2 = 0.f;
    #pragma unroll
    for (int j = 0; j < 4; ++j) {
        s += part[(bg * 4 + j) * 2 + 0];
        s2 += part[(bg * 4 + j) * 2 + 1];
    }
    float mean = s * (1.f / 65536.f);
    float var = s2 * (1.f / 65536.f) - mean * mean;
    float rstd = rsqrtf(var + 1e-5f);

    __shared__ unsigned short tile[64][68];
    #pragma unroll
    for (int i = 0; i < 4; ++i) {
        int nt = q * 4 + i;
        __syncthreads();
        #pragma unroll
        for (int p = 0; p < 4; ++p) {
            int cc = p * 16 + (t >> 4);
            int nn = (t & 15) * 4;
            float4 v = *reinterpret_cast<const float4*>(&xg[(size_t)cc * NN + nt * 64 + nn]);
            float ga = gamma[g * 64 + cc], be = beta[g * 64 + cc];
            float aa = rstd * ga;
            float c0 = be - mean * aa;
            ushort4 pk;
            pk.x = bfb(v.x * aa + c0);
            pk.y = bfb(v.y * aa + c0);
            pk.z = bfb(v.z * aa + c0);
            pk.w = bfb(v.w * aa + c0);
            *reinterpret_cast<ushort4*>(&tile[cc][nn]) = pk;
        }
        __syncthreads();
        #pragma unroll
        for (int p = 0; p < 16; ++p) {
            int nn = p * 4 + (t >> 6);
            int cc = t & 63;
            xnT[((size_t)b * NN + nt * 64 + nn) * CC + g * 64 + cc] = tile[cc][nn];
        }
    }
}

// ---------------- kernel 2: fused QKV projections, BK=64 LDS-staged GEMM (round-9 proven) ----------------
// Q output pre-scaled by QSCALE so attention's exp2 argument is the raw QK dot.
__global__ __launch_bounds__(256, 2) void qkv2_kernel(
    const unsigned short* __restrict__ wqb, const unsigned short* __restrict__ wkb,
    const unsigned short* __restrict__ wvb,
    const float* __restrict__ bq, const float* __restrict__ bk, const float* __restrict__ bv,
    const unsigned short* __restrict__ xnT,
    unsigned short* __restrict__ qt, unsigned short* __restrict__ kt,
    unsigned short* __restrict__ vv) {
    int wg = blockIdx.x;
    int xcd = wg & 7, local = wg >> 3;       // local 0..191
    int mloc = local / 12;                    // 0..15
    int rem = local - mloc * 12;
    int n_tile = rem / 3;                     // 0..3
    int p = rem - n_tile * 3;                 // 0..2
    int m_tile = xcd * 16 + mloc;             // 0..127

    const unsigned short* w = (p == 0) ? wqb : (p == 1) ? wkb : wvb;
    const float* bias = (p == 0) ? bq : (p == 1) ? bk : bv;
    int row0 = m_tile * 128;                  // global (b,n) row
    int o0t = n_tile * 128;                   // output channel base

    __shared__ __align__(16) char As[2][16384];
    __shared__ __align__(16) char Bs[2][16384];

    int t = threadIdx.x;
    int lane = t & 63, wid = t >> 6;
    int Rl = lane >> 3;                       // 0..7 row within 8-row group
    int csw = ((lane & 7) ^ Rl) << 4;         // pre-swizzled source chunk (bytes)

    const char* Ag = (const char*)xnT + (size_t)row0 * 1024;
    const char* Bg = (const char*)w + (size_t)o0t * 1024;

    #pragma unroll
    for (int j = 0; j < 4; ++j) {             // stage k0=0 into buf 0
        int ii = wid * 4 + j;
        size_t ro = (size_t)(ii * 8 + Rl) * 1024 + csw;
        gload_lds16(Ag + ro, &As[0][ii * 1024]);
        gload_lds16(Bg + ro, &Bs[0][ii * 1024]);
    }
    __syncthreads();

    int wr = wid & 1, wc = wid >> 1;          // wave -> 64x64 quadrant
    int lr = lane & 15, lg = lane >> 4;
    f32x4 acc[4][4] = {};

    for (int ks = 0; ks < 8; ++ks) {
        int cb_ = ks & 1;
        if (ks < 7) {
            int k0 = (ks + 1) * 64;
            #pragma unroll
            for (int j = 0; j < 4; ++j) {
                int ii = wid * 4 + j;
                size_t ro = (size_t)(ii * 8 + Rl) * 1024 + k0 * 2 + csw;
                gload_lds16(Ag + ro, &As[cb_ ^ 1][ii * 1024]);
                gload_lds16(Bg + ro, &Bs[cb_ ^ 1][ii * 1024]);
            }
        }
        const char* al = As[cb_];
        const char* bl = Bs[cb_];
        #pragma unroll
        for (int kk = 0; kk < 2; ++kk) {
            bf16x8 wf[4], xf[4];
            #pragma unroll
            for (int r = 0; r < 4; ++r) {
                int row = wc * 64 + r * 16 + lr;
                wf[r] = ldb8(bl + row * 128 + (((kk * 4 + lg) ^ (row & 7)) << 4));
            }
            #pragma unroll
            for (int c = 0; c < 4; ++c) {
                int row = wr * 64 + c * 16 + lr;
                xf[c] = ldb8(al + row * 128 + (((kk * 4 + lg) ^ (row & 7)) << 4));
            }
            __builtin_amdgcn_s_setprio(1);
            #pragma unroll
            for (int r = 0; r < 4; ++r)
                #pragma unroll
                for (int c = 0; c < 4; ++c)
                    acc[r][c] = __builtin_amdgcn_mfma_f32_16x16x32_bf16(wf[r], xf[c], acc[r][c], 0, 0, 0);
            __builtin_amdgcn_s_setprio(0);
        }
        __syncthreads();
    }

    // epilogue
    #pragma unroll
    for (int r = 0; r < 4; ++r) {
        int o0 = o0t + wc * 64 + r * 16 + lg * 4;
        #pragma unroll
        for (int c = 0; c < 4; ++c) {
            int grow = row0 + wr * 64 + c * 16 + lr;
            int b = grow >> 10, n = grow & 1023;
            float v0 = acc[r][c][0] + bias[o0 + 0];
            float v1 = acc[r][c][1] + bias[o0 + 1];
            float v2 = acc[r][c][2] + bias[o0 + 2];
            float v3 = acc[r][c][3] + bias[o0 + 3];
            if (p < 2) {
                if (p == 0) { v0 *= QSCALE; v1 *= QSCALE; v2 *= QSCALE; v3 *= QSCALE; }
                unsigned short* outp = (p == 0) ? qt : kt;
                int h = o0 >> 6, d = o0 & 63;
                ushort4 pk;
                pk.x = bfb(v0); pk.y = bfb(v1); pk.z = bfb(v2); pk.w = bfb(v3);
                *reinterpret_cast<ushort4*>(outp + ((size_t)(b * HHH + h) * NN + n) * DH + d) = pk;
            } else {
                vv[((size_t)b * CC + o0 + 0) * NN + n] = bfb(v0);
                vv[((size_t)b * CC + o0 + 1) * NN + n] = bfb(v1);
                vv[((size_t)b * CC + o0 + 2) * NN + n] = bfb(v2);
                vv[((size_t)b * CC + o0 + 3) * NN + n] = bfb(v3);
            }
        }
    }
}

// ---------------- kernel 3: flash attention, max-free softmax (attn4, best: 47.5us) ----------------
__global__ __launch_bounds__(256, 2) void attn4_kernel(
    const unsigned short* __restrict__ qt, const unsigned short* __restrict__ kt,
    const unsigned short* __restrict__ vv, unsigned short* __restrict__ aoT) {
    int wg = blockIdx.x;
    int bh = ((wg >> 6) << 3) + (wg & 7);  // all 8 qtiles of a head share an XCD
    int qt8 = (wg >> 3) & 7;
    int b = bh >> 3, h = bh & 7;
    int lane = threadIdx.x & 63, wid = threadIdx.x >> 6;
    int nl = lane & 31, hi = lane >> 5;
    int n = qt8 * 128 + wid * 32 + nl;

    const unsigned short* Qb = qt + (size_t)bh * NN * DH;
    const unsigned short* Kb = kt + (size_t)bh * NN * DH;
    const unsigned short* Vb = vv + ((size_t)b * CC + h * DH) * NN;

    __shared__ __align__(16) char smem[2][16384];  // [buf][ K 8KB | V 8KB ]

    const unsigned short* Qp = Qb + (size_t)n * DH + hi * 8;
    bf16x8 qf[4];
    qf[0] = ldb8(Qp);
    qf[1] = ldb8(Qp + 16);
    qf[2] = ldb8(Qp + 32);
    qf[3] = ldb8(Qp + 48);

    int Rl = lane >> 3;                    // 0..7
    int cs16 = 16 * ((lane & 7) ^ Rl);     // pre-swizzled col bytes
    const char* Kc = (const char*)Kb;      // row stride 128B
    const char* Vc = (const char*)Vb;      // row stride 2048B

    #pragma unroll
    for (int j = 0; j < 2; ++j) {
        int ii = 2 * wid + j;
        int R = ii * 8 + Rl;
        gload_lds16(Kc + (size_t)R * 128 + cs16, &smem[0][ii * 1024]);
        gload_lds16(Vc + (size_t)R * 2048 + cs16, &smem[0][8192 + ii * 1024]);
    }
    __syncthreads();

    f32x16 o0 = {}, o1 = {};
    float l_i = 0.f;
    int cur = 0;

    for (int mt = 0; mt < 16; ++mt) {
        if (mt < 15) {
            int m0n = (mt + 1) * 64;
            #pragma unroll
            for (int j = 0; j < 2; ++j) {
                int ii = 2 * wid + j;
                int R = ii * 8 + Rl;
                gload_lds16(Kc + (size_t)(m0n + R) * 128 + cs16, &smem[cur ^ 1][ii * 1024]);
                gload_lds16(Vc + (size_t)R * 2048 + (size_t)m0n * 2 + cs16,
                            &smem[cur ^ 1][8192 + ii * 1024]);
            }
        }

        const char* kl = &smem[cur][0];
        const char* vl = &smem[cur][8192];
        int swz = (nl & 7) << 4;
        int rowA = nl * 128, rowB = (nl + 32) * 128;

        bf16x8 ka[4], kbf[4];
        #pragma unroll
        for (int ks = 0; ks < 4; ++ks) {
            int cb = (hi * 16 + ks * 32) ^ swz;
            ka[ks]  = ldb8(kl + rowA + cb);
            kbf[ks] = ldb8(kl + rowB + cb);
        }

        f32x16 s0 = {}, s1 = {};
        __builtin_amdgcn_s_setprio(1);
        #pragma unroll
        for (int ks = 0; ks < 4; ++ks) {
            s0 = __builtin_amdgcn_mfma_f32_32x32x16_bf16(ka[ks], qf[ks], s0, 0, 0, 0);
            s1 = __builtin_amdgcn_mfma_f32_32x32x16_bf16(kbf[ks], qf[ks], s1, 0, 0, 0);
        }
        __builtin_amdgcn_s_setprio(0);

        bf16x8 va[4], vbf[4];
        #pragma unroll
        for (int ks = 0; ks < 4; ++ks) {
            int cb = (hi * 16 + ks * 32) ^ swz;
            va[ks]  = ldb8(vl + rowA + cb);
            vbf[ks] = ldb8(vl + rowB + cb);
        }

        // ---- max-free softmax: P = 2^S', accumulate l ----
        #pragma unroll
        for (int e = 0; e < 16; ++e) s0[e] = __builtin_amdgcn_exp2f(s0[e]);
        #pragma unroll
        for (int e = 0; e < 16; ++e) s1[e] = __builtin_amdgcn_exp2f(s1[e]);
        float ts[16];
        #pragma unroll
        for (int e = 0; e < 16; ++e) ts[e] = s0[e] + s1[e];
        #pragma unroll
        for (int st = 8; st; st >>= 1)
            #pragma unroll
            for (int e = 0; e < st; ++e) ts[e] += ts[e + st];
        l_i += ts[0];

        // ---- pack P -> bf16 B-fragments (cvt_pk + permlane32_swap) ----
        unsigned pA = cvtpk(s0[0], s0[1]), pB = cvtpk(s0[4], s0[5]);
        asm("v_permlane32_swap_b32 %0, %1" : "+v"(pA), "+v"(pB));
        unsigned pC = cvtpk(s0[2], s0[3]), pD = cvtpk(s0[6], s0[7]);
        asm("v_permlane32_swap_b32 %0, %1" : "+v"(pC), "+v"(pD));
        unsigned pE = cvtpk(s0[8], s0[9]), pF = cvtpk(s0[12], s0[13]);
        asm("v_permlane32_swap_b32 %0, %1" : "+v"(pE), "+v"(pF));
        unsigned pG = cvtpk(s0[10], s0[11]), pH = cvtpk(s0[14], s0[15]);
        asm("v_permlane32_swap_b32 %0, %1" : "+v"(pG), "+v"(pH));
        u32x4 w00 = {pA, pC, pB, pD};
        u32x4 w01 = {pE, pG, pF, pH};
        unsigned qA = cvtpk(s1[0], s1[1]), qB = cvtpk(s1[4], s1[5]);
        asm("v_permlane32_swap_b32 %0, %1" : "+v"(qA), "+v"(qB));
        unsigned qC = cvtpk(s1[2], s1[3]), qD = cvtpk(s1[6], s1[7]);
        asm("v_permlane32_swap_b32 %0, %1" : "+v"(qC), "+v"(qD));
        unsigned qE = cvtpk(s1[8], s1[9]), qF = cvtpk(s1[12], s1[13]);
        asm("v_permlane32_swap_b32 %0, %1" : "+v"(qE), "+v"(qF));
        unsigned qG = cvtpk(s1[10], s1[11]), qH = cvtpk(s1[14], s1[15]);
        asm("v_permlane32_swap_b32 %0, %1" : "+v"(qG), "+v"(qH));
        u32x4 w10 = {qA, qC, qB, qD};
        u32x4 w11 = {qE, qG, qF, qH};

        bf16x8 pa00 = __builtin_bit_cast(bf16x8, w00);
        bf16x8 pa01 = __builtin_bit_cast(bf16x8, w01);
        bf16x8 pa10 = __builtin_bit_cast(bf16x8, w10);
        bf16x8 pa11 = __builtin_bit_cast(bf16x8, w11);

        // ---- PV: O^T[d][n] += V^T[d][m] P^T[m][n] ----
        __builtin_amdgcn_s_setprio(1);
        o0 = __builtin_amdgcn_mfma_f32_32x32x16_bf16(va[0], pa00, o0, 0, 0, 0);
        o0 = __builtin_amdgcn_mfma_f32_32x32x16_bf16(va[1], pa01, o0, 0, 0, 0);
        o0 = __builtin_amdgcn_mfma_f32_32x32x16_bf16(va[2], pa10, o0, 0, 0, 0);
        o0 = __builtin_amdgcn_mfma_f32_32x32x16_bf16(va[3], pa11, o0, 0, 0, 0);
        o1 = __builtin_amdgcn_mfma_f32_32x32x16_bf16(vbf[0], pa00, o1, 0, 0, 0);
        o1 = __builtin_amdgcn_mfma_f32_32x32x16_bf16(vbf[1], pa01, o1, 0, 0, 0);
        o1 = __builtin_amdgcn_mfma_f32_32x32x16_bf16(vbf[2], pa10, o1, 0, 0, 0);
        o1 = __builtin_amdgcn_mfma_f32_32x32x16_bf16(vbf[3], pa11, o1, 0, 0, 0);
        __builtin_amdgcn_s_setprio(0);

        __syncthreads();
        cur ^= 1;
    }

    // merge the hi-half partial denominators once, normalize, write aoT
    float l = l_i + __shfl_xor(l_i, 32);
    float inv = 1.f / l;
    unsigned short* op = aoT + ((size_t)b * NN + n) * CC + h * DH;
    #pragma unroll
    for (int q = 0; q < 4; ++q) {
        ushort4 pk;
        pk.x = bfb(o0[4 * q + 0] * inv);
        pk.y = bfb(o0[4 * q + 1] * inv);
        pk.z = bfb(o0[4 * q + 2] * inv);
        pk.w = bfb(o0[4 * q + 3] * inv);
        *reinterpret_cast<ushort4*>(op + q * 8 + hi * 4) = pk;
        ushort4 pk2;
        pk2.x = bfb(o1[4 * q + 0] * inv);
        pk2.y = bfb(o1[4 * q + 1] * inv);
        pk2.z = bfb(o1[4 * q + 2] * inv);
        pk2.w = bfb(o1[4 * q + 3] * inv);
        *reinterpret_cast<ushort4*>(op + 32 + q * 8 + hi * 4) = pk2;
    }
}

// ---------------- kernel 4: output projection, BK=64 LDS-staged GEMM + bias + residual ----------------
__global__ __launch_bounds__(256, 2) void oproj2_kernel(
    const unsigned short* __restrict__ wob, const float* __restrict__ bo,
    const unsigned short* __restrict__ aoT, const float* __restrict__ x,
    float* __restrict__ out) {
    int wg = blockIdx.x;
    int xcd = wg & 7, local = wg >> 3;        // local 0..63
    int mloc = local >> 2;                     // 0..15
    int n_tile = local & 3;                    // 0..3
    int m_tile = xcd * 16 + mloc;              // 0..127
    int row0 = m_tile * 128;
    int o0t = n_tile * 128;

    __shared__ __align__(16) char As[2][16384];
    __shared__ __align__(16) char Bs[2][16384];

    int t = threadIdx.x;
    int lane = t & 63, wid = t >> 6;
    int Rl = lane >> 3;
    int csw = ((lane & 7) ^ Rl) << 4;

    const char* Ag = (const char*)aoT + (size_t)row0 * 1024;
    const char* Bg = (const char*)wob + (size_t)o0t * 1024;

    #pragma unroll
    for (int j = 0; j < 4; ++j) {
        int ii = wid * 4 + j;
        size_t ro = (size_t)(ii * 8 + Rl) * 1024 + csw;
        gload_lds16(Ag + ro, &As[0][ii * 1024]);
        gload_lds16(Bg + ro, &Bs[0][ii * 1024]);
    }
    __syncthreads();

    int wr = wid & 1, wc = wid >> 1;
    int lr = lane & 15, lg = lane >> 4;
    f32x4 acc[4][4] = {};

    for (int ks = 0; ks < 8; ++ks) {
        int cb_ = ks & 1;
        if (ks < 7) {
            int k0 = (ks + 1) * 64;
            #pragma unroll
            for (int j = 0; j < 4; ++j) {
                int ii = wid * 4 + j;
                size_t ro = (size_t)(ii * 8 + Rl) * 1024 + k0 * 2 + csw;
                gload_lds16(Ag + ro, &As[cb_ ^ 1][ii * 1024]);
                gload_lds16(Bg + ro, &Bs[cb_ ^ 1][ii * 1024]);
            }
        }
        const char* al = As[cb_];
        const char* bl = Bs[cb_];
        #pragma unroll
        for (int kk = 0; kk < 2; ++kk) {
            bf16x8 wf[4], xf[4];
            #pragma unroll
            for (int r = 0; r < 4; ++r) {
                int row = wc * 64 + r * 16 + lr;
                wf[r] = ldb8(bl + row * 128 + (((kk * 4 + lg) ^ (row & 7)) << 4));
            }
            #pragma unroll
            for (int c = 0; c < 4; ++c) {
                int row = wr * 64 + c * 16 + lr;
                xf[c] = ldb8(al + row * 128 + (((kk * 4 + lg) ^ (row & 7)) << 4));
            }
            __builtin_amdgcn_s_setprio(1);
            #pragma unroll
            for (int r = 0; r < 4; ++r)
                #pragma unroll
                for (int c = 0; c < 4; ++c)
                    acc[r][c] = __builtin_amdgcn_mfma_f32_16x16x32_bf16(wf[r], xf[c], acc[r][c], 0, 0, 0);
            __builtin_amdgcn_s_setprio(0);
        }
        __syncthreads();
    }

    #pragma unroll
    for (int r = 0; r < 4; ++r) {
        int o0 = o0t + wc * 64 + r * 16 + lg * 4;
        #pragma unroll
        for (int c = 0; c < 4; ++c) {
            int grow = row0 + wr * 64 + c * 16 + lr;
            int b = grow >> 10, n = grow & 1023;
            #pragma unroll
            for (int j = 0; j < 4; ++j) {
                size_t idx = ((size_t)b * CC + o0 + j) * NN + n;
                out[idx] = acc[r][c][j] + bo[o0 + j] + x[idx];
            }
        }
    }
}

extern "C" void kernel_launch(void* const* d_in, const int* in_sizes, int n_in,
                              void* d_out, int out_size, void* d_ws, size_t ws_size,
                              hipStream_t stream) {
    const float* x     = (const float*)d_in[0];
    const float* wq    = (const float*)d_in[1];
    const float* bq    = (const float*)d_in[2];
    const float* wk    = (const float*)d_in[3];
    const float* bk    = (const float*)d_in[4];
    const float* wv    = (const float*)d_in[5];
    const float* bv    = (const float*)d_in[6];
    const float* wo    = (const float*)d_in[7];
    const float* bo    = (const float*)d_in[8];
    const float* gamma = (const float*)d_in[9];
    const float* beta  = (const float*)d_in[10];

    char* ws = (char*)d_ws;
    const size_t WSZ = (size_t)CC * CC * 2;           // 512 KB per weight
    const size_t TEN = (size_t)BB * NN * CC * 2;      // 16.78 MB per tensor
    unsigned short* wqb = (unsigned short*)(ws);
    unsigned short* wkb = (unsigned short*)(ws + WSZ);
    unsigned short* wvb = (unsigned short*)(ws + 2 * WSZ);
    unsigned short* wob = (unsigned short*)(ws + 3 * WSZ);
    unsigned short* xnT = (unsigned short*)(ws + 4 * WSZ);
    unsigned short* qt  = (unsigned short*)(ws + 4 * WSZ + TEN);
    unsigned short* kt  = (unsigned short*)(ws + 4 * WSZ + 2 * TEN);
    unsigned short* vv  = (unsigned short*)(ws + 4 * WSZ + 3 * TEN);
    unsigned short* aoT = (unsigned short*)(ws + 4 * WSZ + 4 * TEN);
    float* part         = (float*)(ws + 4 * WSZ + 5 * TEN);   // 512*2 floats

    statsconv_kernel<<<dim3(768), dim3(256), 0, stream>>>(
        x, (const float4*)wq, (const float4*)wk, (const float4*)wv, (const float4*)wo,
        (ushort4*)wqb, (ushort4*)wkb, (ushort4*)wvb, (ushort4*)wob, part);
    gn_apply_kernel<<<dim3(512), dim3(256), 0, stream>>>(x, gamma, beta, part, xnT);
    qkv2_kernel<<<dim3(1536), dim3(256), 0, stream>>>(
        wqb, wkb, wvb, bq, bk, bv, xnT, qt, kt, vv);
    attn4_kernel<<<dim3(1024), dim3(256), 0, stream>>>(qt, kt, vv, aoT);
    oproj2_kernel<<<dim3(512), dim3(256), 0, stream>>>(wob, bo, aoT, x, (float*)d_out);
}

// Round 12
// 122.806 us; speedup vs baseline: 1.0401x; 1.0042x over previous
//
#include <hip/hip_runtime.h>
#include <hip/hip_bf16.h>

#define BB 16
#define CC 512
#define NN 1024
#define GG 8
#define HHH 8
#define DH 64

typedef __bf16 bf16x8 __attribute__((ext_vector_type(8)));
typedef float f32x4 __attribute__((ext_vector_type(4)));
typedef float f32x16 __attribute__((ext_vector_type(16)));
typedef unsigned int u32x4 __attribute__((ext_vector_type(4)));

// scale * log2(e), folded into Q at projection time so S' = q'.k is the exp2 argument
#define QSCALE 0.18033688011116027f

__device__ __forceinline__ unsigned short bfb(float f) {
    __hip_bfloat16 h = __float2bfloat16(f);
    return __builtin_bit_cast(unsigned short, h);
}

__device__ __forceinline__ bf16x8 ldb8(const void* p) {
    return *reinterpret_cast<const bf16x8*>(p);
}

__device__ __forceinline__ unsigned int cvtpk(float lo, float hi) {
    unsigned int r;
    asm("v_cvt_pk_bf16_f32 %0, %1, %2" : "=v"(r) : "v"(lo), "v"(hi));
    return r;
}

typedef const __attribute__((address_space(1))) unsigned int* gas_ptr;
typedef __attribute__((address_space(3))) unsigned int* las_ptr;
__device__ __forceinline__ void gload_lds16(const void* g, void* l) {
    __builtin_amdgcn_global_load_lds((gas_ptr)g, (las_ptr)l, 16, 0, 0);
}

// ---------------- kernel A: GN partial stats (blocks 0..511) + weight conversion (512..767) ----------------
__global__ __launch_bounds__(256) void statsconv_kernel(
    const float* __restrict__ x,
    const float4* __restrict__ wq, const float4* __restrict__ wk,
    const float4* __restrict__ wv, const float4* __restrict__ wo,
    ushort4* __restrict__ oq, ushort4* __restrict__ ok2,
    ushort4* __restrict__ ov, ushort4* __restrict__ oo,
    float* __restrict__ part) {
    int blk = blockIdx.x;
    int t = threadIdx.x;
    if (blk < 512) {
        int bg = blk >> 2, q = blk & 3;
        const float* xg = x + (size_t)bg * 65536 + q * 256;  // 64 rows x 256 cols quarter
        float s = 0.f, s2 = 0.f;
        #pragma unroll
        for (int i = 0; i < 16; ++i) {
            int c = i * 256 + t;           // 4096 float4 chunks
            int row = c >> 6, col = c & 63;
            float4 v = *reinterpret_cast<const float4*>(xg + (size_t)row * 1024 + col * 4);
            s += v.x + v.y + v.z + v.w;
            s2 += v.x * v.x + v.y * v.y + v.z * v.z + v.w * v.w;
        }
        #pragma unroll
        for (int m = 1; m < 64; m <<= 1) {
            s += __shfl_xor(s, m);
            s2 += __shfl_xor(s2, m);
        }
        __shared__ float red[2][4];
        int wid = t >> 6;
        if ((t & 63) == 0) { red[0][wid] = s; red[1][wid] = s2; }
        __syncthreads();
        if (t == 0) {
            part[blk * 2 + 0] = red[0][0] + red[0][1] + red[0][2] + red[0][3];
            part[blk * 2 + 1] = red[1][0] + red[1][1] + red[1][2] + red[1][3];
        }
    } else {
        int i = (blk - 512) * 256 + t;     // over C*C/4 = 65536
        float4 a;
        ushort4 r;
        a = wq[i]; r.x = bfb(a.x); r.y = bfb(a.y); r.z = bfb(a.z); r.w = bfb(a.w); oq[i] = r;
        a = wk[i]; r.x = bfb(a.x); r.y = bfb(a.y); r.z = bfb(a.z); r.w = bfb(a.w); ok2[i] = r;
        a = wv[i]; r.x = bfb(a.x); r.y = bfb(a.y); r.z = bfb(a.z); r.w = bfb(a.w); ov[i] = r;
        a = wo[i]; r.x = bfb(a.x); r.y = bfb(a.y); r.z = bfb(a.z); r.w = bfb(a.w); oo[i] = r;
    }
}

// ---------------- kernel B: GN apply + transpose -> xnT [B][N][C] bf16 (512 blocks) ----------------
__global__ __launch_bounds__(256) void gn_apply_kernel(
    const float* __restrict__ x, const float* __restrict__ gamma,
    const float* __restrict__ beta, const float* __restrict__ part,
    unsigned short* __restrict__ xnT) {
    int blk = blockIdx.x;
    int bg = blk >> 2, q = blk & 3;
    int b = bg >> 3, g = bg & 7;
    const float* xg = x + (size_t)bg * 65536;
    int t = threadIdx.x;

    // finalize stats from the 4 quarter-partials (fixed order -> deterministic)
    float s = 0.f, s2 = 0.f;
    #pragma unroll
    for (int j = 0; j < 4; ++j) {
        s += part[(bg * 4 + j) * 2 + 0];
        s2 += part[(bg * 4 + j) * 2 + 1];
    }
    float mean = s * (1.f / 65536.f);
    float var = s2 * (1.f / 65536.f) - mean * mean;
    float rstd = rsqrtf(var + 1e-5f);

    __shared__ unsigned short tile[64][68];
    #pragma unroll
    for (int i = 0; i < 4; ++i) {
        int nt = q * 4 + i;
        __syncthreads();
        #pragma unroll
        for (int p = 0; p < 4; ++p) {
            int cc = p * 16 + (t >> 4);
            int nn = (t & 15) * 4;
            float4 v = *reinterpret_cast<const float4*>(&xg[(size_t)cc * NN + nt * 64 + nn]);
            float ga = gamma[g * 64 + cc], be = beta[g * 64 + cc];
            float aa = rstd * ga;
            float c0 = be - mean * aa;
            ushort4 pk;
            pk.x = bfb(v.x * aa + c0);
            pk.y = bfb(v.y * aa + c0);
            pk.z = bfb(v.z * aa + c0);
            pk.w = bfb(v.w * aa + c0);
            *reinterpret_cast<ushort4*>(&tile[cc][nn]) = pk;
        }
        __syncthreads();
        #pragma unroll
        for (int p = 0; p < 16; ++p) {
            int nn = p * 4 + (t >> 6);
            int cc = t & 63;
            xnT[((size_t)b * NN + nt * 64 + nn) * CC + g * 64 + cc] = tile[cc][nn];
        }
    }
}

// ---------------- kernel 2: fused QKV projections, BK=64 LDS-staged GEMM ----------------
// Q output pre-scaled by QSCALE so attention's exp2 argument is the raw QK dot.
__global__ __launch_bounds__(256, 2) void qkv2_kernel(
    const unsigned short* __restrict__ wqb, const unsigned short* __restrict__ wkb,
    const unsigned short* __restrict__ wvb,
    const float* __restrict__ bq, const float* __restrict__ bk, const float* __restrict__ bv,
    const unsigned short* __restrict__ xnT,
    unsigned short* __restrict__ qt, unsigned short* __restrict__ kt,
    unsigned short* __restrict__ vv) {
    int wg = blockIdx.x;
    int xcd = wg & 7, local = wg >> 3;       // local 0..191
    int mloc = local / 12;                    // 0..15
    int rem = local - mloc * 12;
    int n_tile = rem / 3;                     // 0..3
    int p = rem - n_tile * 3;                 // 0..2
    int m_tile = xcd * 16 + mloc;             // 0..127

    const unsigned short* w = (p == 0) ? wqb : (p == 1) ? wkb : wvb;
    const float* bias = (p == 0) ? bq : (p == 1) ? bk : bv;
    int row0 = m_tile * 128;                  // global (b,n) row
    int o0t = n_tile * 128;                   // output channel base

    __shared__ __align__(16) char As[2][16384];
    __shared__ __align__(16) char Bs[2][16384];

    int t = threadIdx.x;
    int lane = t & 63, wid = t >> 6;
    int Rl = lane >> 3;                       // 0..7 row within 8-row group
    int csw = ((lane & 7) ^ Rl) << 4;         // pre-swizzled source chunk (bytes)

    const char* Ag = (const char*)xnT + (size_t)row0 * 1024;
    const char* Bg = (const char*)w + (size_t)o0t * 1024;

    #pragma unroll
    for (int j = 0; j < 4; ++j) {             // stage k0=0 into buf 0
        int ii = wid * 4 + j;
        size_t ro = (size_t)(ii * 8 + Rl) * 1024 + csw;
        gload_lds16(Ag + ro, &As[0][ii * 1024]);
        gload_lds16(Bg + ro, &Bs[0][ii * 1024]);
    }
    __syncthreads();

    int wr = wid & 1, wc = wid >> 1;          // wave -> 64x64 quadrant
    int lr = lane & 15, lg = lane >> 4;
    f32x4 acc[4][4] = {};

    for (int ks = 0; ks < 8; ++ks) {
        int cb_ = ks & 1;
        if (ks < 7) {
            int k0 = (ks + 1) * 64;
            #pragma unroll
            for (int j = 0; j < 4; ++j) {
                int ii = wid * 4 + j;
                size_t ro = (size_t)(ii * 8 + Rl) * 1024 + k0 * 2 + csw;
                gload_lds16(Ag + ro, &As[cb_ ^ 1][ii * 1024]);
                gload_lds16(Bg + ro, &Bs[cb_ ^ 1][ii * 1024]);
            }
        }
        const char* al = As[cb_];
        const char* bl = Bs[cb_];
        #pragma unroll
        for (int kk = 0; kk < 2; ++kk) {
            bf16x8 wf[4], xf[4];
            #pragma unroll
            for (int r = 0; r < 4; ++r) {
                int row = wc * 64 + r * 16 + lr;
                wf[r] = ldb8(bl + row * 128 + (((kk * 4 + lg) ^ (row & 7)) << 4));
            }
            #pragma unroll
            for (int c = 0; c < 4; ++c) {
                int row = wr * 64 + c * 16 + lr;
                xf[c] = ldb8(al + row * 128 + (((kk * 4 + lg) ^ (row & 7)) << 4));
            }
            __builtin_amdgcn_s_setprio(1);
            #pragma unroll
            for (int r = 0; r < 4; ++r)
                #pragma unroll
                for (int c = 0; c < 4; ++c)
                    acc[r][c] = __builtin_amdgcn_mfma_f32_16x16x32_bf16(wf[r], xf[c], acc[r][c], 0, 0, 0);
            __builtin_amdgcn_s_setprio(0);
        }
        __syncthreads();
    }

    // epilogue
    #pragma unroll
    for (int r = 0; r < 4; ++r) {
        int o0 = o0t + wc * 64 + r * 16 + lg * 4;
        #pragma unroll
        for (int c = 0; c < 4; ++c) {
            int grow = row0 + wr * 64 + c * 16 + lr;
            int b = grow >> 10, n = grow & 1023;
            float v0 = acc[r][c][0] + bias[o0 + 0];
            float v1 = acc[r][c][1] + bias[o0 + 1];
            float v2 = acc[r][c][2] + bias[o0 + 2];
            float v3 = acc[r][c][3] + bias[o0 + 3];
            if (p < 2) {
                if (p == 0) { v0 *= QSCALE; v1 *= QSCALE; v2 *= QSCALE; v3 *= QSCALE; }
                unsigned short* outp = (p == 0) ? qt : kt;
                int h = o0 >> 6, d = o0 & 63;
                ushort4 pk;
                pk.x = bfb(v0); pk.y = bfb(v1); pk.z = bfb(v2); pk.w = bfb(v3);
                *reinterpret_cast<ushort4*>(outp + ((size_t)(b * HHH + h) * NN + n) * DH + d) = pk;
            } else {
                vv[((size_t)b * CC + o0 + 0) * NN + n] = bfb(v0);
                vv[((size_t)b * CC + o0 + 1) * NN + n] = bfb(v1);
                vv[((size_t)b * CC + o0 + 2) * NN + n] = bfb(v2);
                vv[((size_t)b * CC + o0 + 3) * NN + n] = bfb(v3);
            }
        }
    }
}

// ---------------- kernel 3: flash attention, 2 q-tiles/block + ring-of-3 counted-vmcnt ----------------
// (round-6 attn5: measured 46.4-46.7us, the session best; restored against the fixed pipeline)
__global__ __launch_bounds__(256, 2) void attn5_kernel(
    const unsigned short* __restrict__ qt, const unsigned short* __restrict__ kt,
    const unsigned short* __restrict__ vv, unsigned short* __restrict__ aoT) {
    int wg = blockIdx.x;                    // 512 = 128 bh x 4 qpair
    int xcd = wg & 7;
    int qp = (wg >> 3) & 3;
    int bh = ((wg >> 5) << 3) | xcd;        // all 4 q-pair blocks of a head on one XCD
    int b = bh >> 3, h = bh & 7;
    int lane = threadIdx.x & 63, wid = threadIdx.x >> 6;
    int nl = lane & 31, hi = lane >> 5;
    int nA = qp * 256 + wid * 32 + nl;      // q-tile A row
    int nB = nA + 128;                      // q-tile B row

    const unsigned short* Qb = qt + (size_t)bh * NN * DH;
    const unsigned short* Kb = kt + (size_t)bh * NN * DH;
    const unsigned short* Vb = vv + ((size_t)b * CC + h * DH) * NN;

    __shared__ __align__(16) char smem[3][16384];  // ring: [K 8KB | V 8KB] each

    const unsigned short* QpA = Qb + (size_t)nA * DH + hi * 8;
    const unsigned short* QpB = Qb + (size_t)nB * DH + hi * 8;
    bf16x8 qfA[4], qfB[4];
    #pragma unroll
    for (int ks = 0; ks < 4; ++ks) {
        qfA[ks] = ldb8(QpA + ks * 16);
        qfB[ks] = ldb8(QpB + ks * 16);
    }

    int Rl = lane >> 3;                    // 0..7
    int cs16 = 16 * ((lane & 7) ^ Rl);     // pre-swizzled col bytes (T2, rule #21)
    const char* Kc = (const char*)Kb;      // key rows, 128B stride
    const char* Vc = (const char*)Vb;      // d rows, 2048B stride

    #define STAGE(tt, buf)                                                        \
        {                                                                         \
            int m0_ = (tt) * 64;                                                  \
            _Pragma("unroll")                                                     \
            for (int j = 0; j < 2; ++j) {                                         \
                int ii = 2 * wid + j;                                             \
                int R = ii * 8 + Rl;                                              \
                gload_lds16(Kc + (size_t)(m0_ + R) * 128 + cs16,                  \
                            &smem[buf][ii * 1024]);                               \
                gload_lds16(Vc + (size_t)R * 2048 + (size_t)m0_ * 2 + cs16,       \
                            &smem[buf][8192 + ii * 1024]);                        \
            }                                                                     \
        }

    STAGE(0, 0);
    STAGE(1, 1);

    f32x16 oA0 = {}, oA1 = {}, oB0 = {}, oB1 = {};
    float lA = 0.f, lB = 0.f;

    for (int mt = 0; mt < 16; ++mt) {
        // counted wait: tile-mt's 4 loads are the oldest; tile-(mt+1)'s stay in flight
        if (mt < 15) asm volatile("s_waitcnt vmcnt(4)" ::: "memory");
        else         asm volatile("s_waitcnt vmcnt(0)" ::: "memory");
        __builtin_amdgcn_s_barrier();
        if (mt < 14) STAGE(mt + 2, (mt + 2) % 3);

        const char* kl = &smem[mt % 3][0];
        const char* vl = &smem[mt % 3][8192];
        int swz = (nl & 7) << 4;
        int rowA = nl * 128, rowB = (nl + 32) * 128;

        // K fragments read once, feed both q-tiles
        bf16x8 ka[4], kbf[4];
        #pragma unroll
        for (int ks = 0; ks < 4; ++ks) {
            int cb = (hi * 16 + ks * 32) ^ swz;
            ka[ks]  = ldb8(kl + rowA + cb);
            kbf[ks] = ldb8(kl + rowB + cb);
        }

        f32x16 sA0 = {}, sA1 = {}, sB0 = {}, sB1 = {};
        __builtin_amdgcn_s_setprio(1);
        #pragma unroll
        for (int ks = 0; ks < 4; ++ks) {
            sA0 = __builtin_amdgcn_mfma_f32_32x32x16_bf16(ka[ks],  qfA[ks], sA0, 0, 0, 0);
            sA1 = __builtin_amdgcn_mfma_f32_32x32x16_bf16(kbf[ks], qfA[ks], sA1, 0, 0, 0);
            sB0 = __builtin_amdgcn_mfma_f32_32x32x16_bf16(ka[ks],  qfB[ks], sB0, 0, 0, 0);
            sB1 = __builtin_amdgcn_mfma_f32_32x32x16_bf16(kbf[ks], qfB[ks], sB1, 0, 0, 0);
        }
        __builtin_amdgcn_s_setprio(0);

        // V fragments read once, feed both PVs
        bf16x8 va[4], vbf[4];
        #pragma unroll
        for (int ks = 0; ks < 4; ++ks) {
            int cb = (hi * 16 + ks * 32) ^ swz;
            va[ks]  = ldb8(vl + rowA + cb);
            vbf[ks] = ldb8(vl + rowB + cb);
        }

        // ---------- q-tile A: exp2, l-sum, pack, PV ----------
        #pragma unroll
        for (int e = 0; e < 16; ++e) sA0[e] = __builtin_amdgcn_exp2f(sA0[e]);
        #pragma unroll
        for (int e = 0; e < 16; ++e) sA1[e] = __builtin_amdgcn_exp2f(sA1[e]);
        {
            float ts[16];
            #pragma unroll
            for (int e = 0; e < 16; ++e) ts[e] = sA0[e] + sA1[e];
            #pragma unroll
            for (int st = 8; st; st >>= 1)
                #pragma unroll
                for (int e = 0; e < st; ++e) ts[e] += ts[e + st];
            lA += ts[0];
        }
        {
            unsigned pA = cvtpk(sA0[0], sA0[1]), pB = cvtpk(sA0[4], sA0[5]);
            asm("v_permlane32_swap_b32 %0, %1" : "+v"(pA), "+v"(pB));
            unsigned pC = cvtpk(sA0[2], sA0[3]), pD = cvtpk(sA0[6], sA0[7]);
            asm("v_permlane32_swap_b32 %0, %1" : "+v"(pC), "+v"(pD));
            unsigned pE = cvtpk(sA0[8], sA0[9]), pF = cvtpk(sA0[12], sA0[13]);
            asm("v_permlane32_swap_b32 %0, %1" : "+v"(pE), "+v"(pF));
            unsigned pG = cvtpk(sA0[10], sA0[11]), pH = cvtpk(sA0[14], sA0[15]);
            asm("v_permlane32_swap_b32 %0, %1" : "+v"(pG), "+v"(pH));
            u32x4 w00 = {pA, pC, pB, pD};
            u32x4 w01 = {pE, pG, pF, pH};
            unsigned qA = cvtpk(sA1[0], sA1[1]), qB = cvtpk(sA1[4], sA1[5]);
            asm("v_permlane32_swap_b32 %0, %1" : "+v"(qA), "+v"(qB));
            unsigned qC = cvtpk(sA1[2], sA1[3]), qD = cvtpk(sA1[6], sA1[7]);
            asm("v_permlane32_swap_b32 %0, %1" : "+v"(qC), "+v"(qD));
            unsigned qE = cvtpk(sA1[8], sA1[9]), qF = cvtpk(sA1[12], sA1[13]);
            asm("v_permlane32_swap_b32 %0, %1" : "+v"(qE), "+v"(qF));
            unsigned qG = cvtpk(sA1[10], sA1[11]), qH = cvtpk(sA1[14], sA1[15]);
            asm("v_permlane32_swap_b32 %0, %1" : "+v"(qG), "+v"(qH));
            u32x4 w10 = {qA, qC, qB, qD};
            u32x4 w11 = {qE, qG, qF, qH};
            bf16x8 pa00 = __builtin_bit_cast(bf16x8, w00);
            bf16x8 pa01 = __builtin_bit_cast(bf16x8, w01);
            bf16x8 pa10 = __builtin_bit_cast(bf16x8, w10);
            bf16x8 pa11 = __builtin_bit_cast(bf16x8, w11);
            __builtin_amdgcn_s_setprio(1);
            oA0 = __builtin_amdgcn_mfma_f32_32x32x16_bf16(va[0],  pa00, oA0, 0, 0, 0);
            oA0 = __builtin_amdgcn_mfma_f32_32x32x16_bf16(va[1],  pa01, oA0, 0, 0, 0);
            oA0 = __builtin_amdgcn_mfma_f32_32x32x16_bf16(va[2],  pa10, oA0, 0, 0, 0);
            oA0 = __builtin_amdgcn_mfma_f32_32x32x16_bf16(va[3],  pa11, oA0, 0, 0, 0);
            oA1 = __builtin_amdgcn_mfma_f32_32x32x16_bf16(vbf[0], pa00, oA1, 0, 0, 0);
            oA1 = __builtin_amdgcn_mfma_f32_32x32x16_bf16(vbf[1], pa01, oA1, 0, 0, 0);
            oA1 = __builtin_amdgcn_mfma_f32_32x32x16_bf16(vbf[2], pa10, oA1, 0, 0, 0);
            oA1 = __builtin_amdgcn_mfma_f32_32x32x16_bf16(vbf[3], pa11, oA1, 0, 0, 0);
            __builtin_amdgcn_s_setprio(0);
        }

        // ---------- q-tile B: exp2, l-sum, pack, PV ----------
        #pragma unroll
        for (int e = 0; e < 16; ++e) sB0[e] = __builtin_amdgcn_exp2f(sB0[e]);
        #pragma unroll
        for (int e = 0; e < 16; ++e) sB1[e] = __builtin_amdgcn_exp2f(sB1[e]);
        {
            float ts[16];
            #pragma unroll
            for (int e = 0; e < 16; ++e) ts[e] = sB0[e] + sB1[e];
            #pragma unroll
            for (int st = 8; st; st >>= 1)
                #pragma unroll
                for (int e = 0; e < st; ++e) ts[e] += ts[e + st];
            lB += ts[0];
        }
        {
            unsigned pA = cvtpk(sB0[0], sB0[1]), pB = cvtpk(sB0[4], sB0[5]);
            asm("v_permlane32_swap_b32 %0, %1" : "+v"(pA), "+v"(pB));
            unsigned pC = cvtpk(sB0[2], sB0[3]), pD = cvtpk(sB0[6], sB0[7]);
            asm("v_permlane32_swap_b32 %0, %1" : "+v"(pC), "+v"(pD));
            unsigned pE = cvtpk(sB0[8], sB0[9]), pF = cvtpk(sB0[12], sB0[13]);
            asm("v_permlane32_swap_b32 %0, %1" : "+v"(pE), "+v"(pF));
            unsigned pG = cvtpk(sB0[10], sB0[11]), pH = cvtpk(sB0[14], sB0[15]);
            asm("v_permlane32_swap_b32 %0, %1" : "+v"(pG), "+v"(pH));
            u32x4 w00 = {pA, pC, pB, pD};
            u32x4 w01 = {pE, pG, pF, pH};
            unsigned qA = cvtpk(sB1[0], sB1[1]), qB = cvtpk(sB1[4], sB1[5]);
            asm("v_permlane32_swap_b32 %0, %1" : "+v"(qA), "+v"(qB));
            unsigned qC = cvtpk(sB1[2], sB1[3]), qD = cvtpk(sB1[6], sB1[7]);
            asm("v_permlane32_swap_b32 %0, %1" : "+v"(qC), "+v"(qD));
            unsigned qE = cvtpk(sB1[8], sB1[9]), qF = cvtpk(sB1[12], sB1[13]);
            asm("v_permlane32_swap_b32 %0, %1" : "+v"(qE), "+v"(qF));
            unsigned qG = cvtpk(sB1[10], sB1[11]), qH = cvtpk(sB1[14], sB1[15]);
            asm("v_permlane32_swap_b32 %0, %1" : "+v"(qG), "+v"(qH));
            u32x4 w10 = {qA, qC, qB, qD};
            u32x4 w11 = {qE, qG, qF, qH};
            bf16x8 pb00 = __builtin_bit_cast(bf16x8, w00);
            bf16x8 pb01 = __builtin_bit_cast(bf16x8, w01);
            bf16x8 pb10 = __builtin_bit_cast(bf16x8, w10);
            bf16x8 pb11 = __builtin_bit_cast(bf16x8, w11);
            __builtin_amdgcn_s_setprio(1);
            oB0 = __builtin_amdgcn_mfma_f32_32x32x16_bf16(va[0],  pb00, oB0, 0, 0, 0);
            oB0 = __builtin_amdgcn_mfma_f32_32x32x16_bf16(va[1],  pb01, oB0, 0, 0, 0);
            oB0 = __builtin_amdgcn_mfma_f32_32x32x16_bf16(va[2],  pb10, oB0, 0, 0, 0);
            oB0 = __builtin_amdgcn_mfma_f32_32x32x16_bf16(va[3],  pb11, oB0, 0, 0, 0);
            oB1 = __builtin_amdgcn_mfma_f32_32x32x16_bf16(vbf[0], pb00, oB1, 0, 0, 0);
            oB1 = __builtin_amdgcn_mfma_f32_32x32x16_bf16(vbf[1], pb01, oB1, 0, 0, 0);
            oB1 = __builtin_amdgcn_mfma_f32_32x32x16_bf16(vbf[2], pb10, oB1, 0, 0, 0);
            oB1 = __builtin_amdgcn_mfma_f32_32x32x16_bf16(vbf[3], pb11, oB1, 0, 0, 0);
            __builtin_amdgcn_s_setprio(0);
        }
    }
    #undef STAGE

    // merge hi-half denominators, normalize, write both tiles
    float lAm = lA + __shfl_xor(lA, 32);
    float lBm = lB + __shfl_xor(lB, 32);
    float invA = 1.f / lAm, invB = 1.f / lBm;
    unsigned short* opA = aoT + ((size_t)b * NN + nA) * CC + h * DH;
    unsigned short* opB = aoT + ((size_t)b * NN + nB) * CC + h * DH;
    #pragma unroll
    for (int q = 0; q < 4; ++q) {
        ushort4 pk;
        pk.x = bfb(oA0[4 * q + 0] * invA);
        pk.y = bfb(oA0[4 * q + 1] * invA);
        pk.z = bfb(oA0[4 * q + 2] * invA);
        pk.w = bfb(oA0[4 * q + 3] * invA);
        *reinterpret_cast<ushort4*>(opA + q * 8 + hi * 4) = pk;
        pk.x = bfb(oA1[4 * q + 0] * invA);
        pk.y = bfb(oA1[4 * q + 1] * invA);
        pk.z = bfb(oA1[4 * q + 2] * invA);
        pk.w = bfb(oA1[4 * q + 3] * invA);
        *reinterpret_cast<ushort4*>(opA + 32 + q * 8 + hi * 4) = pk;
        pk.x = bfb(oB0[4 * q + 0] * invB);
        pk.y = bfb(oB0[4 * q + 1] * invB);
        pk.z = bfb(oB0[4 * q + 2] * invB);
        pk.w = bfb(oB0[4 * q + 3] * invB);
        *reinterpret_cast<ushort4*>(opB + q * 8 + hi * 4) = pk;
        pk.x = bfb(oB1[4 * q + 0] * invB);
        pk.y = bfb(oB1[4 * q + 1] * invB);
        pk.z = bfb(oB1[4 * q + 2] * invB);
        pk.w = bfb(oB1[4 * q + 3] * invB);
        *reinterpret_cast<ushort4*>(opB + 32 + q * 8 + hi * 4) = pk;
    }
}

// ---------------- kernel 4: output projection, BK=64 LDS-staged GEMM + bias + residual ----------------
__global__ __launch_bounds__(256, 2) void oproj2_kernel(
    const unsigned short* __restrict__ wob, const float* __restrict__ bo,
    const unsigned short* __restrict__ aoT, const float* __restrict__ x,
    float* __restrict__ out) {
    int wg = blockIdx.x;
    int xcd = wg & 7, local = wg >> 3;        // local 0..63
    int mloc = local >> 2;                     // 0..15
    int n_tile = local & 3;                    // 0..3
    int m_tile = xcd * 16 + mloc;              // 0..127
    int row0 = m_tile * 128;
    int o0t = n_tile * 128;

    __shared__ __align__(16) char As[2][16384];
    __shared__ __align__(16) char Bs[2][16384];

    int t = threadIdx.x;
    int lane = t & 63, wid = t >> 6;
    int Rl = lane >> 3;
    int csw = ((lane & 7) ^ Rl) << 4;

    const char* Ag = (const char*)aoT + (size_t)row0 * 1024;
    const char* Bg = (const char*)wob + (size_t)o0t * 1024;

    #pragma unroll
    for (int j = 0; j < 4; ++j) {
        int ii = wid * 4 + j;
        size_t ro = (size_t)(ii * 8 + Rl) * 1024 + csw;
        gload_lds16(Ag + ro, &As[0][ii * 1024]);
        gload_lds16(Bg + ro, &Bs[0][ii * 1024]);
    }
    __syncthreads();

    int wr = wid & 1, wc = wid >> 1;
    int lr = lane & 15, lg = lane >> 4;
    f32x4 acc[4][4] = {};

    for (int ks = 0; ks < 8; ++ks) {
        int cb_ = ks & 1;
        if (ks < 7) {
            int k0 = (ks + 1) * 64;
            #pragma unroll
            for (int j = 0; j < 4; ++j) {
                int ii = wid * 4 + j;
                size_t ro = (size_t)(ii * 8 + Rl) * 1024 + k0 * 2 + csw;
                gload_lds16(Ag + ro, &As[cb_ ^ 1][ii * 1024]);
                gload_lds16(Bg + ro, &Bs[cb_ ^ 1][ii * 1024]);
            }
        }
        const char* al = As[cb_];
        const char* bl = Bs[cb_];
        #pragma unroll
        for (int kk = 0; kk < 2; ++kk) {
            bf16x8 wf[4], xf[4];
            #pragma unroll
            for (int r = 0; r < 4; ++r) {
                int row = wc * 64 + r * 16 + lr;
                wf[r] = ldb8(bl + row * 128 + (((kk * 4 + lg) ^ (row & 7)) << 4));
            }
            #pragma unroll
            for (int c = 0; c < 4; ++c) {
                int row = wr * 64 + c * 16 + lr;
                xf[c] = ldb8(al + row * 128 + (((kk * 4 + lg) ^ (row & 7)) << 4));
            }
            __builtin_amdgcn_s_setprio(1);
            #pragma unroll
            for (int r = 0; r < 4; ++r)
                #pragma unroll
                for (int c = 0; c < 4; ++c)
                    acc[r][c] = __builtin_amdgcn_mfma_f32_16x16x32_bf16(wf[r], xf[c], acc[r][c], 0, 0, 0);
            __builtin_amdgcn_s_setprio(0);
        }
        __syncthreads();
    }

    #pragma unroll
    for (int r = 0; r < 4; ++r) {
        int o0 = o0t + wc * 64 + r * 16 + lg * 4;
        #pragma unroll
        for (int c = 0; c < 4; ++c) {
            int grow = row0 + wr * 64 + c * 16 + lr;
            int b = grow >> 10, n = grow & 1023;
            #pragma unroll
            for (int j = 0; j < 4; ++j) {
                size_t idx = ((size_t)b * CC + o0 + j) * NN + n;
                out[idx] = acc[r][c][j] + bo[o0 + j] + x[idx];
            }
        }
    }
}

extern "C" void kernel_launch(void* const* d_in, const int* in_sizes, int n_in,
                              void* d_out, int out_size, void* d_ws, size_t ws_size,
                              hipStream_t stream) {
    const float* x     = (const float*)d_in[0];
    const float* wq    = (const float*)d_in[1];
    const float* bq    = (const float*)d_in[2];
    const float* wk    = (const float*)d_in[3];
    const float* bk    = (const float*)d_in[4];
    const float* wv    = (const float*)d_in[5];
    const float* bv    = (const float*)d_in[6];
    const float* wo    = (const float*)d_in[7];
    const float* bo    = (const float*)d_in[8];
    const float* gamma = (const float*)d_in[9];
    const float* beta  = (const float*)d_in[10];

    char* ws = (char*)d_ws;
    const size_t WSZ = (size_t)CC * CC * 2;           // 512 KB per weight
    const size_t TEN = (size_t)BB * NN * CC * 2;      // 16.78 MB per tensor
    unsigned short* wqb = (unsigned short*)(ws);
    unsigned short* wkb = (unsigned short*)(ws + WSZ);
    unsigned short* wvb = (unsigned short*)(ws + 2 * WSZ);
    unsigned short* wob = (unsigned short*)(ws + 3 * WSZ);
    unsigned short* xnT = (unsigned short*)(ws + 4 * WSZ);
    unsigned short* qt  = (unsigned short*)(ws + 4 * WSZ + TEN);
    unsigned short* kt  = (unsigned short*)(ws + 4 * WSZ + 2 * TEN);
    unsigned short* vv  = (unsigned short*)(ws + 4 * WSZ + 3 * TEN);
    unsigned short* aoT = (unsigned short*)(ws + 4 * WSZ + 4 * TEN);
    float* part         = (float*)(ws + 4 * WSZ + 5 * TEN);   // 512*2 floats

    statsconv_kernel<<<dim3(768), dim3(256), 0, stream>>>(
        x, (const float4*)wq, (const float4*)wk, (const float4*)wv, (const float4*)wo,
        (ushort4*)wqb, (ushort4*)wkb, (ushort4*)wvb, (ushort4*)wob, part);
    gn_apply_kernel<<<dim3(512), dim3(256), 0, stream>>>(x, gamma, beta, part, xnT);
    qkv2_kernel<<<dim3(1536), dim3(256), 0, stream>>>(
        wqb, wkb, wvb, bq, bk, bv, xnT, qt, kt, vv);
    attn5_kernel<<<dim3(512), dim3(256), 0, stream>>>(qt, kt, vv, aoT);
    oproj2_kernel<<<dim3(512), dim3(256), 0, stream>>>(wob, bo, aoT, x, (float*)d_out);
}